// Round 3
// baseline (1250.159 us; speedup 1.0000x reference)
//
#include <hip/hip_runtime.h>
#include <hip/hip_bf16.h>

// Problem: N=2048, F_IN=128, F_OUT=64
// out[j,f] = sum_{i,k} A[j,i] H[i,f] mh[i,k] H[k,f] mf[j,k],  H = X@W + b
// R3: barrier-free main loop. Each wave stages its own private 64x64x32
// double-buffered tiles via global_load_lds and self-syncs with
// s_waitcnt vmcnt(8) (distance-1 prefetch). Two NAMED LDS buffers + 2x
// unrolled loop keep alias analysis precise (no compiler vmcnt(0)).

typedef __attribute__((ext_vector_type(8))) _Float16 f16x8;
typedef __attribute__((ext_vector_type(4))) _Float16 f16x4;
typedef __attribute__((ext_vector_type(4))) float f32x4;

#define N 2048
#define FOUT 64
#define FIN 128
#define NIT 1024   // 16 ktiles * 64 i-steps of 32

__device__ __forceinline__ void gl_lds16(const _Float16* g, _Float16* l) {
    __builtin_amdgcn_global_load_lds(
        (const __attribute__((address_space(1))) void*)g,
        (__attribute__((address_space(3))) void*)l, 16, 0, 0);
}

// ---------------- prep kernels ----------------

__global__ __launch_bounds__(256) void k_h(const float* __restrict__ X,
                                           const float* __restrict__ W,
                                           const float* __restrict__ bias,
                                           float* __restrict__ HT,
                                           _Float16* __restrict__ HTh) {
    __shared__ float Ws[FIN * FOUT];
    __shared__ float Xs[4 * FIN];
    int t = threadIdx.x;
#pragma unroll
    for (int s = 0; s < 32; ++s) Ws[t + 256 * s] = W[t + 256 * s];
    int i0 = blockIdx.x * 4;
#pragma unroll
    for (int s = 0; s < 2; ++s) { int idx = t + 256 * s; Xs[idx] = X[(size_t)i0 * FIN + idx]; }
    __syncthreads();
    int f = t & 63, il = t >> 6;
    float h = bias[f];
#pragma unroll
    for (int p = 0; p < FIN; ++p) h = fmaf(Xs[il * FIN + p], Ws[p * FOUT + f], h);
    int i = i0 + il;
    HT[f * N + i] = h;
    HTh[f * N + i] = (_Float16)h;
}

__global__ __launch_bounds__(256) void k_a2h(const float* __restrict__ A,
                                             _Float16* __restrict__ Ah) {
    int g = blockIdx.x * 256 + threadIdx.x;
    float4 v = ((const float4*)A)[g];
    f16x4 o;
    o[0] = (_Float16)v.x; o[1] = (_Float16)v.y; o[2] = (_Float16)v.z; o[3] = (_Float16)v.w;
    ((f16x4*)Ah)[g] = o;
}

__global__ __launch_bounds__(256) void k_mht(const float* __restrict__ mh,
                                             _Float16* __restrict__ mhT) {
    __shared__ float tile[64][65];
    int t = threadIdx.x;
    int bx = blockIdx.x & 31;
    int by = blockIdx.x >> 5;
#pragma unroll
    for (int s = 0; s < 16; ++s) {
        int lin = t + 256 * s;
        int r = lin >> 6, c = lin & 63;
        tile[r][c] = mh[(size_t)(by * 64 + r) * N + bx * 64 + c];
    }
    __syncthreads();
#pragma unroll
    for (int s = 0; s < 16; ++s) {
        int lin = t + 256 * s;
        int kr = lin >> 6, ic = lin & 63;
        mhT[(size_t)(bx * 64 + kr) * N + by * 64 + ic] = (_Float16)tile[ic][kr];
    }
}

// ---------------- main kernel ----------------
// grid 512 = 16 jtiles * 32 fgroups; 256 threads; block = 128j x 128k x 2f.
// Wave w: wj=(w&1)*64, wk=(w>>1)*64. Wave-private LDS tiles (64 rows x 32
// halves per operand per buffer), XOR-granule swizzled.

// issue 8 global_load_lds calls for iteration it_ into (la_, lb_)
#define ISSUE(it_, la_, lb_)                                                  \
    {                                                                         \
        int ib_ = ((it_) & 63) << 5;                                          \
        int kb_ = ((it_) >> 6) << 7;                                          \
        const _Float16* pa_ = Ah + aoff + ib_;                                \
        const _Float16* pb_ = mhT + boff + (size_t)kb_ * N + ib_;             \
        _Pragma("unroll") for (int c_ = 0; c_ < 4; ++c_) {                    \
            gl_lds16(pa_ + c_ * 16 * N, (la_) + c_ * 512);                    \
            gl_lds16(pb_ + c_ * 16 * N, (lb_) + c_ * 512);                    \
        }                                                                     \
    }

#define EPILOGUE(kt_)                                                         \
    {                                                                         \
        int kbase_ = (kt_) << 7;                                              \
        _Pragma("unroll") for (int jj = 0; jj < 4; ++jj) {                    \
            float t0_[4] = {0.f, 0.f, 0.f, 0.f};                              \
            float t1_[4] = {0.f, 0.f, 0.f, 0.f};                              \
            _Pragma("unroll") for (int kk = 0; kk < 4; ++kk) {                \
                int kg_ = kbase_ + wk + kk * 16 + l16;                        \
                float hk0_ = HT[f0 * N + kg_];                                \
                float hk1_ = HT[(f0 + 1) * N + kg_];                          \
                int jrow_ = jbase + wj + jj * 16 + q * 4;                     \
                _Pragma("unroll") for (int r = 0; r < 4; ++r) {               \
                    float m_ = mf[(size_t)(jrow_ + r) * N + kg_];             \
                    t0_[r] = fmaf(acc[0][jj][kk][r], m_ * hk0_, t0_[r]);      \
                    t1_[r] = fmaf(acc[1][jj][kk][r], m_ * hk1_, t1_[r]);      \
                }                                                             \
            }                                                                 \
            _Pragma("unroll") for (int r = 0; r < 4; ++r) {                   \
                float v0_ = t0_[r], v1_ = t1_[r];                             \
                v0_ += __shfl_xor(v0_, 1); v1_ += __shfl_xor(v1_, 1);         \
                v0_ += __shfl_xor(v0_, 2); v1_ += __shfl_xor(v1_, 2);         \
                v0_ += __shfl_xor(v0_, 4); v1_ += __shfl_xor(v1_, 4);         \
                v0_ += __shfl_xor(v0_, 8); v1_ += __shfl_xor(v1_, 8);         \
                outp[0][jj][r] += v0_;                                        \
                outp[1][jj][r] += v1_;                                        \
            }                                                                 \
        }                                                                     \
        _Pragma("unroll") for (int a_ = 0; a_ < 2; ++a_)                      \
            _Pragma("unroll") for (int b_ = 0; b_ < 4; ++b_)                  \
                _Pragma("unroll") for (int c2_ = 0; c2_ < 4; ++c2_)           \
                    acc[a_][b_][c2_] = (f32x4){0.f, 0.f, 0.f, 0.f};           \
    }

#define COMPUTE(it_, ta_, tb_, do_epi_)                                       \
    {                                                                         \
        int ib_ = ((it_) & 63) << 5;                                          \
        f16x8 ar_[4], br_[4];                                                 \
        _Pragma("unroll") for (int x = 0; x < 4; ++x)                         \
            ar_[x] = *(const f16x8*)&(ta_)[(x * 16 + l16) * 32 + pcq];        \
        _Pragma("unroll") for (int x = 0; x < 4; ++x)                         \
            br_[x] = *(const f16x8*)&(tb_)[(x * 16 + l16) * 32 + pcq];        \
        f16x8 h0_ = *(const f16x8*)&hbuf[0][ib_ + (q << 3)];                  \
        f16x8 h1_ = *(const f16x8*)&hbuf[1][ib_ + (q << 3)];                  \
        _Pragma("unroll") for (int jj = 0; jj < 4; ++jj) {                    \
            f16x8 a0_ = ar_[jj] * h0_;                                        \
            f16x8 a1_ = ar_[jj] * h1_;                                        \
            _Pragma("unroll") for (int kk = 0; kk < 4; ++kk) {                \
                acc[0][jj][kk] = __builtin_amdgcn_mfma_f32_16x16x32_f16(      \
                    a0_, br_[kk], acc[0][jj][kk], 0, 0, 0);                   \
                acc[1][jj][kk] = __builtin_amdgcn_mfma_f32_16x16x32_f16(      \
                    a1_, br_[kk], acc[1][jj][kk], 0, 0, 0);                   \
            }                                                                 \
        }                                                                     \
        if ((do_epi_) && (((it_) & 63) == 63)) { EPILOGUE((it_) >> 6); }      \
    }

__global__ __launch_bounds__(256, 2) void k_main(const float* __restrict__ mf,
                                                 const float* __restrict__ HT,
                                                 const _Float16* __restrict__ HTh,
                                                 const _Float16* __restrict__ Ah,
                                                 const _Float16* __restrict__ mhT,
                                                 float* __restrict__ out) {
    // two NAMED buffers (alias-analysis-distinct): [wave][op][64*32]
    __shared__ _Float16 tile0[4][2][2048];   // 32 KB
    __shared__ _Float16 tile1[4][2][2048];   // 32 KB
    __shared__ _Float16 hbuf[2][N];          // 8 KB
    __shared__ float red[2][4][64];          // 2 KB

    int t = threadIdx.x;
    int jbase = (blockIdx.x >> 5) << 7;
    int f0 = (blockIdx.x & 31) << 1;
    int w = t >> 6, lane = t & 63, q = lane >> 4, l16 = lane & 15;
    int wj = (w & 1) << 6, wk = (w >> 1) << 6;

    // stage H rows once
#pragma unroll
    for (int s = 0; s < 2; ++s) {
        int idx = t + 256 * s;
        ((f16x8*)hbuf)[idx] = *(const f16x8*)&HTh[(size_t)(f0 + (idx >> 8)) * N + (idx & 255) * 8];
    }
    __syncthreads();

    // per-lane staging constants: lane l -> LDS byte l*16
    int lrow = lane >> 2;                       // 0..15 row within 16-row call
    int lc = ((lane & 3) - (lrow >> 1)) & 3;    // global chunk to fetch (un-swizzle)
    size_t aoff = (size_t)(jbase + wj + lrow) * N + lc * 8;
    size_t boff = (size_t)(wk + lrow) * N + lc * 8;    // + kb*N per ktile

    _Float16* la0 = &tile0[w][0][0];
    _Float16* lb0 = &tile0[w][1][0];
    _Float16* la1 = &tile1[w][0][0];
    _Float16* lb1 = &tile1[w][1][0];

    // fragment-read swizzled chunk offset (halves)
    int pcq = ((q + (l16 >> 1)) & 3) << 3;

    float outp[2][4][4];
    f32x4 acc[2][4][4];
#pragma unroll
    for (int a = 0; a < 2; ++a)
#pragma unroll
        for (int b = 0; b < 4; ++b)
#pragma unroll
            for (int c = 0; c < 4; ++c) {
                outp[a][b][c] = 0.f;
                acc[a][b][c] = (f32x4){0.f, 0.f, 0.f, 0.f};
            }

    ISSUE(0, la0, lb0);

#pragma unroll 1
    for (int it2 = 0; it2 < NIT; it2 += 2) {
        // ---- step A: prefetch it2+1 -> tile1, compute it2 from tile0 ----
        ISSUE(it2 + 1, la1, lb1);
        __builtin_amdgcn_sched_barrier(0);
        __builtin_amdgcn_s_waitcnt(0x0F78);   // vmcnt <= 8 (it2's loads done)
        __builtin_amdgcn_sched_barrier(0);
        COMPUTE(it2, la0, lb0, 0);

        // ---- step B: prefetch it2+2 -> tile0, compute it2+1 from tile1 ----
        if (it2 + 2 < NIT) {
            ISSUE(it2 + 2, la0, lb0);
            __builtin_amdgcn_sched_barrier(0);
            __builtin_amdgcn_s_waitcnt(0x0F78);
            __builtin_amdgcn_sched_barrier(0);
        } else {
            __builtin_amdgcn_sched_barrier(0);
            __builtin_amdgcn_s_waitcnt(0x0F70);   // vmcnt(0)
            __builtin_amdgcn_sched_barrier(0);
        }
        COMPUTE(it2 + 1, la1, lb1, 1);
    }

    // cross-wave reduce + store
    if (l16 == 0) {
#pragma unroll
        for (int fi = 0; fi < 2; ++fi)
#pragma unroll
            for (int jj = 0; jj < 4; ++jj)
#pragma unroll
                for (int r = 0; r < 4; ++r)
                    red[fi][w][jj * 16 + q * 4 + r] = outp[fi][jj][r];
    }
    __syncthreads();
    if (t < 128) {
        int j = t;
#pragma unroll
        for (int fi = 0; fi < 2; ++fi) {
            float v = (j < 64) ? (red[fi][0][j] + red[fi][2][j])
                               : (red[fi][1][j - 64] + red[fi][3][j - 64]);
            out[(size_t)(jbase + j) * FOUT + f0 + fi] = v;
        }
    }
}

// ---------------- launch ----------------
extern "C" void kernel_launch(void* const* d_in, const int* in_sizes, int n_in,
                              void* d_out, int out_size, void* d_ws, size_t ws_size,
                              hipStream_t stream) {
    const float* X    = (const float*)d_in[0];
    const float* A    = (const float*)d_in[1];
    const float* mf   = (const float*)d_in[2];
    const float* mh   = (const float*)d_in[3];
    const float* W    = (const float*)d_in[4];
    const float* bias = (const float*)d_in[5];
    float* out = (float*)d_out;

    float*    HT  = (float*)d_ws;
    _Float16* HTh = (_Float16*)((char*)d_ws + 524288);
    _Float16* Ah  = (_Float16*)((char*)d_ws + 1048576);
    _Float16* mhT = (_Float16*)((char*)d_ws + 1048576 + 8388608);

    k_h<<<N / 4, 256, 0, stream>>>(X, W, bias, HT, HTh);
    k_a2h<<<(N * N / 4) / 256, 256, 0, stream>>>(A, Ah);
    k_mht<<<(N / 64) * (N / 64), 256, 0, stream>>>(mh, mhT);
    k_main<<<16 * 32, 256, 0, stream>>>(mf, HT, HTh, Ah, mhT, out);
}